// Round 11
// baseline (336.310 us; speedup 1.0000x reference)
//
#include <hip/hip_runtime.h>
#include <hip/hip_bf16.h>

#define BATCH 4
#define SEQ   1024
#define DIM   1024
#define NH    16
#define DH    64
#define DFF   4096
#define MTOK  (BATCH*SEQ)   // 4096 token rows

// log2(e)/8 : folded into Q so attention softmax runs in base-2 (exact).
#define QSCALE 0.1803368801111204f

typedef __attribute__((ext_vector_type(8))) short  short8;
typedef __attribute__((ext_vector_type(4))) float  floatx4;
typedef __attribute__((ext_vector_type(4))) float  float4v;

__device__ inline float bf2f(short s) {
    return __uint_as_float(((unsigned int)(unsigned short)s) << 16);
}
__device__ inline short f2bf(float f) {
    __hip_bfloat16 h = __float2bfloat16(f);
    return *reinterpret_cast<short*>(&h);
}

__device__ inline float wave_sum(float v) {
    #pragma unroll
    for (int off = 32; off >= 1; off >>= 1) v += __shfl_xor(v, off);
    return v;
}

// async global->LDS, 16B per lane; LDS dst = wave-uniform base + lane*16.
__device__ inline void async_ld16(short* lds, const short* g) {
    __builtin_amdgcn_global_load_lds(
        (const __attribute__((address_space(1))) void*)g,
        (__attribute__((address_space(3))) void*)lds, 16, 0, 0);
}

// ---------------------------------------------------------------------------
// Fused fp32->bf16 conversion of all 6 tensors in ONE launch.
// ---------------------------------------------------------------------------
__global__ __launch_bounds__(256) void convert_all(
    const float* __restrict__ sX,  short* __restrict__ dX,
    const float* __restrict__ sq,  short* __restrict__ dq,
    const float* __restrict__ sk,  short* __restrict__ dk,
    const float* __restrict__ sv,  short* __restrict__ dv,
    const float* __restrict__ s1,  short* __restrict__ d1,
    const float* __restrict__ s2,  short* __restrict__ d2)
{
    int cid = blockIdx.x * 256 + threadIdx.x;     // 0 .. 1966079
    const float* src; short* dst; int base;
    if      (cid <  524288) { src = sX; dst = dX; base = 0; }
    else if (cid <  655360) { src = sq; dst = dq; base = 524288; }
    else if (cid <  786432) { src = sk; dst = dk; base = 655360; }
    else if (cid <  917504) { src = sv; dst = dv; base = 786432; }
    else if (cid < 1441792) { src = s1; dst = d1; base = 917504; }
    else                    { src = s2; dst = d2; base = 1441792; }
    size_t i = (size_t)(cid - base) * 8;
    float4v f0 = *(const float4v*)(src + i);
    float4v f1 = *(const float4v*)(src + i + 4);
    short8 o;
    o[0]=f2bf(f0[0]); o[1]=f2bf(f0[1]); o[2]=f2bf(f0[2]); o[3]=f2bf(f0[3]);
    o[4]=f2bf(f1[0]); o[5]=f2bf(f1[1]); o[6]=f2bf(f1[2]); o[7]=f2bf(f1[3]);
    *(short8*)(dst + i) = o;
}

// ---------------------------------------------------------------------------
// V transpose: V[b][key][h*64+d] -> Vt[(b*16+h)][d][key]  (per-head K-major).
// ---------------------------------------------------------------------------
__global__ __launch_bounds__(256) void transpose_v(
    const short* __restrict__ V, short* __restrict__ Vt)
{
    __shared__ __align__(16) short Tl[64][72];
    const int t  = threadIdx.x;
    const int j0 = blockIdx.x * 64;
    const int bh = blockIdx.y;
    const int b  = bh >> 4;
    const int h  = bh & 15;
    const short* Vb = V + (size_t)b * SEQ * DIM + (size_t)h * DH;

    const int kk = t >> 2, cs = (t & 3) * 16;
    short8 v0 = *(const short8*)(Vb + (size_t)(j0 + kk) * DIM + cs);
    short8 v1 = *(const short8*)(Vb + (size_t)(j0 + kk) * DIM + cs + 8);
    *(short8*)&Tl[kk][cs]     = v0;
    *(short8*)&Tl[kk][cs + 8] = v1;
    __syncthreads();

    const int dd = t >> 2, ks = (t & 3) * 16;
    short8 o0, o1;
    #pragma unroll
    for (int e = 0; e < 8; e++) { o0[e] = Tl[ks + e][dd]; o1[e] = Tl[ks + 8 + e][dd]; }
    short* dst = Vt + ((size_t)bh * DH + dd) * SEQ + j0 + ks;
    *(short8*)(dst)     = o0;
    *(short8*)(dst + 8) = o1;
}

// ---------------------------------------------------------------------------
// NT GEMM, async staging + PING-PONG LDS double buffer:
// C[M,N]=A[M,K]*B[N,K]^T, bf16, fp32 accum. 128 x BN tile, BK=32, 256 thr
// (4 waves 2x2). Tile k+1's global_load_lds is issued into buf^1 BEFORE
// computing tile k from buf, so the barrier's vmcnt drain lands after
// ~300 cy of MFMA (hidden) instead of immediately after issue (R9's flaw).
// One barrier per iteration. No ds_writes (R10's LDS-traffic cost removed).
// EPI: 0 = QKV split store (Q pre-scaled by QSCALE); 1 = +bias,SELU;
//      2 = +bias,+resid(bf16)
// ---------------------------------------------------------------------------
template<int BN, int EPI>
__global__ __launch_bounds__(256) void gemm128(
    const short* __restrict__ A, const short* __restrict__ B,
    const float* __restrict__ bias, const short* __restrict__ resid,
    short* __restrict__ C, int N, int K)
{
    constexpr int NSUB = BN / 32;
    __shared__ __align__(16) short As[2][128*32];   // 2 x 8 KB
    __shared__ __align__(16) short Bs[2][BN*32];    // 2 x 8/4 KB

    const int t    = threadIdx.x;
    const int lane = t & 63;
    const int wave = t >> 6;
    const int quad = lane >> 4;
    const int l15  = lane & 15;
    const int wm   = wave & 1;
    const int wn   = wave >> 1;
    const int tm   = blockIdx.x * 128;
    const int tn   = blockIdx.y * BN;

    const size_t aoff0 = (size_t)(tm + (t >> 2)) * K + (t & 3) * 8;
    const size_t aoff1 = aoff0 + (size_t)64 * K;
    const size_t boff0 = (size_t)(tn + (t >> 2)) * K + (t & 3) * 8;
    const size_t boff1 = boff0 + (size_t)64 * K;

    floatx4 acc[4][NSUB];
    #pragma unroll
    for (int mt = 0; mt < 4; mt++)
        #pragma unroll
        for (int nt = 0; nt < NSUB; nt++) acc[mt][nt] = {0.f, 0.f, 0.f, 0.f};

    auto stage = [&](int k0, int bf) {
        async_ld16(As[bf] + t*8,        A + aoff0 + k0);
        async_ld16(As[bf] + 2048 + t*8, A + aoff1 + k0);
        async_ld16(Bs[bf] + t*8,        B + boff0 + k0);
        if (BN == 128) async_ld16(Bs[bf] + 2048 + t*8, B + boff1 + k0);
    };

    stage(0, 0);
    __syncthreads();                       // prologue drain (once)

    int bf = 0;
    for (int k0 = 0; k0 < K; k0 += 32) {
        if (k0 + 32 < K) stage(k0 + 32, bf ^ 1);   // in flight during compute

        short8 a[4], b[NSUB];
        #pragma unroll
        for (int mt = 0; mt < 4; mt++)
            a[mt] = *(const short8*)&As[bf][(wm*64 + mt*16 + l15)*32 + quad*8];
        #pragma unroll
        for (int nt = 0; nt < NSUB; nt++)
            b[nt] = *(const short8*)&Bs[bf][(wn*(BN/2) + nt*16 + l15)*32 + quad*8];
        #pragma unroll
        for (int mt = 0; mt < 4; mt++)
            #pragma unroll
            for (int nt = 0; nt < NSUB; nt++)
                acc[mt][nt] = __builtin_amdgcn_mfma_f32_16x16x32_bf16(
                                  a[mt], b[nt], acc[mt][nt], 0, 0, 0);

        __syncthreads();                   // drains vmcnt AFTER compute
        bf ^= 1;
    }

    const float SS = 1.0507009873554805f;
    const float SA = 1.6732632423543772f;

    #pragma unroll
    for (int mt = 0; mt < 4; mt++) {
        #pragma unroll
        for (int nt = 0; nt < NSUB; nt++) {
            int col = tn + wn*(BN/2) + nt*16 + l15;
            #pragma unroll
            for (int r = 0; r < 4; r++) {
                int row = tm + wm*64 + mt*16 + quad*4 + r;
                float v = acc[mt][nt][r];
                if (EPI == 0) {
                    int which = col >> 10;
                    if (which == 0) v *= QSCALE;   // base-2 softmax fold
                    C[(size_t)which * ((size_t)MTOK*1024)
                      + (size_t)row * 1024 + (col & 1023)] = f2bf(v);
                } else if (EPI == 1) {
                    v += bias[col];
                    v = (v > 0.f) ? SS * v
                                  : SS * SA * (exp2f(v * 1.44269504f) - 1.f);
                    C[(size_t)row * N + col] = f2bf(v);
                } else {
                    v += bias[col] + bf2f(resid[(size_t)row * N + col]);
                    C[(size_t)row * N + col] = f2bf(v);
                }
            }
        }
    }
}

// ---------------------------------------------------------------------------
// MFMA flash attention, 128-row Q-tile, ping-pong LDS-staged K/V.
// Same single-barrier pipeline as gemm128. Grid = (SEQ/128, BATCH*NH),
// long q-blocks dispatched first. Base-2 fixed-m softmax (R8-validated),
// ones-MFMA row-sum.
// ---------------------------------------------------------------------------
__global__ __launch_bounds__(256) void attn_kernel(
    const short* __restrict__ Q, const short* __restrict__ K,
    const short* __restrict__ Vt, short* __restrict__ CTX)
{
    __shared__ __align__(16) short Ks[2][64*64];    // [key][d], 2 x 8 KB
    __shared__ __align__(16) short Vs[2][64*64];    // [d][key], 2 x 8 KB
    __shared__ __align__(16) short Pl[4][32][72];   // [wave][qrow][key], 18 KB

    const int t    = threadIdx.x;
    const int lane = t & 63;
    const int wave = t >> 6;
    const int quad = lane >> 4;
    const int l15  = lane & 15;
    const int q0 = (gridDim.x - 1 - blockIdx.x) * 128;   // long blocks first
    const int bh = blockIdx.y;
    const int b  = bh >> 4;
    const int h  = bh & 15;

    const size_t headoff = (size_t)b * SEQ * DIM + (size_t)h * DH;
    const short* Qb  = Q + headoff;
    const short* Kb  = K + headoff;
    const short* Vtb = Vt + (size_t)bh * DH * SEQ;   // [d][key]

    const int wrow0 = q0 + wave*32;                  // wave's first q-row

    short8 aq[2][2];
    #pragma unroll
    for (int mg = 0; mg < 2; mg++)
        #pragma unroll
        for (int c = 0; c < 2; c++)
            aq[mg][c] = *(const short8*)(Qb
                + (size_t)(wrow0 + mg*16 + l15) * DIM + c*32 + quad*8);

    short8 bones;
    {
        short v = (l15 == 0) ? (short)0x3F80 : (short)0;
        #pragma unroll
        for (int e = 0; e < 8; e++) bones[e] = v;
    }

    floatx4 o[2][4], ol[2];
    #pragma unroll
    for (int mg = 0; mg < 2; mg++) {
        #pragma unroll
        for (int nt = 0; nt < 4; nt++) o[mg][nt] = {0.f, 0.f, 0.f, 0.f};
        ol[mg] = {0.f, 0.f, 0.f, 0.f};
    }

    auto stage = [&](int j0, int sb) {
        #pragma unroll
        for (int p = 0; p < 2; p++) {
            async_ld16(Ks[sb] + (t + p*256)*8,
                       Kb + (size_t)(j0 + (t>>3) + p*32) * DIM + (t&7)*8);
            async_ld16(Vs[sb] + (t + p*256)*8,
                       Vtb + (size_t)((t>>3) + p*32) * SEQ + j0 + (t&7)*8);
        }
    };

    const int jend = q0 + 128;
    stage(0, 0);
    __syncthreads();

    int sb = 0;
    for (int j0 = 0; j0 < jend; j0 += 64) {
        if (j0 + 64 < jend) stage(j0 + 64, sb ^ 1);

        if (j0 <= wrow0 + 31) {              // not fully masked for this wave
            floatx4 s[2][4];
            #pragma unroll
            for (int mg = 0; mg < 2; mg++)
                #pragma unroll
                for (int nt = 0; nt < 4; nt++) s[mg][nt] = {0.f, 0.f, 0.f, 0.f};
            #pragma unroll
            for (int c = 0; c < 2; c++) {
                #pragma unroll
                for (int nt = 0; nt < 4; nt++) {
                    short8 bk = *(const short8*)&Ks[sb][(nt*16 + l15)*64 + c*32 + quad*8];
                    s[0][nt] = __builtin_amdgcn_mfma_f32_16x16x32_bf16(aq[0][c], bk, s[0][nt], 0, 0, 0);
                    s[1][nt] = __builtin_amdgcn_mfma_f32_16x16x32_bf16(aq[1][c], bk, s[1][nt], 0, 0, 0);
                }
            }

            if (j0 + 63 > wrow0) {           // diagonal region: causal mask
                #pragma unroll
                for (int mg = 0; mg < 2; mg++) {
                    #pragma unroll
                    for (int nt = 0; nt < 4; nt++) {
                        int col = j0 + nt*16 + l15;
                        #pragma unroll
                        for (int r = 0; r < 4; r++) {
                            int rowq = wrow0 + mg*16 + quad*4 + r;
                            if (col > rowq) s[mg][nt][r] = -1.0e38f;
                        }
                    }
                }
            }

            #pragma unroll
            for (int mg = 0; mg < 2; mg++)
                #pragma unroll
                for (int nt = 0; nt < 4; nt++)
                    #pragma unroll
                    for (int r = 0; r < 4; r++)
                        Pl[wave][mg*16 + quad*4 + r][nt*16 + l15]
                            = f2bf(exp2f(s[mg][nt][r]));

            #pragma unroll
            for (int c = 0; c < 2; c++) {
                short8 ap0 = *(const short8*)&Pl[wave][l15][c*32 + quad*8];
                short8 ap1 = *(const short8*)&Pl[wave][16 + l15][c*32 + quad*8];
                #pragma unroll
                for (int nt = 0; nt < 4; nt++) {
                    short8 bv = *(const short8*)&Vs[sb][(nt*16 + l15)*64 + c*32 + quad*8];
                    o[0][nt] = __builtin_amdgcn_mfma_f32_16x16x32_bf16(ap0, bv, o[0][nt], 0, 0, 0);
                    o[1][nt] = __builtin_amdgcn_mfma_f32_16x16x32_bf16(ap1, bv, o[1][nt], 0, 0, 0);
                }
                ol[0] = __builtin_amdgcn_mfma_f32_16x16x32_bf16(ap0, bones, ol[0], 0, 0, 0);
                ol[1] = __builtin_amdgcn_mfma_f32_16x16x32_bf16(ap1, bones, ol[1], 0, 0, 0);
            }
        }

        __syncthreads();                     // drains vmcnt after compute
        sb ^= 1;
    }

    #pragma unroll
    for (int mg = 0; mg < 2; mg++) {
        float linv[4];
        #pragma unroll
        for (int r = 0; r < 4; r++)
            linv[r] = 1.f / __shfl(ol[mg][r], lane & 48);
        #pragma unroll
        for (int nt = 0; nt < 4; nt++) {
            #pragma unroll
            for (int r = 0; r < 4; r++) {
                int rowq = wrow0 + mg*16 + quad*4 + r;
                int d    = nt*16 + l15;
                CTX[(size_t)b * SEQ * DIM + (size_t)rowq * DIM + h*DH + d]
                    = f2bf(o[mg][nt][r] * linv[r]);
            }
        }
    }
}

// ---------------------------------------------------------------------------
// Row LayerNorm over D=1024. xa fp32 or bf16; optional bf16 residual added.
// OUTF32: 1 -> float out (final), 0 -> bf16 out (intermediate).
// ---------------------------------------------------------------------------
template<int OUTF32>
__global__ __launch_bounds__(256) void ln_kernel(
    const void* __restrict__ xav, int xa_fp32, const short* __restrict__ xb,
    const float* __restrict__ g, const float* __restrict__ bvec,
    void* __restrict__ outv)
{
    __shared__ float red[8];
    const size_t base = (size_t)blockIdx.x * DIM;
    const int wave = threadIdx.x >> 6;

    float x[4];
    float sum = 0.f, sq = 0.f;
    #pragma unroll
    for (int i = 0; i < 4; i++) {
        int idx = threadIdx.x + i*256;
        float v = xa_fp32 ? ((const float*)xav)[base + idx]
                          : bf2f(((const short*)xav)[base + idx]);
        if (xb) v += bf2f(xb[base + idx]);
        x[i] = v; sum += v; sq += v*v;
    }
    sum = wave_sum(sum); sq = wave_sum(sq);
    if ((threadIdx.x & 63) == 0) { red[wave] = sum; red[4 + wave] = sq; }
    __syncthreads();
    float s1 = red[0] + red[1] + red[2] + red[3];
    float s2 = red[4] + red[5] + red[6] + red[7];
    float mean = s1 * (1.f / DIM);
    float var  = s2 * (1.f / DIM) - mean * mean;
    float rstd = rsqrtf(var + 1e-5f);
    #pragma unroll
    for (int i = 0; i < 4; i++) {
        int idx = threadIdx.x + i*256;
        float r = (x[i] - mean) * rstd * g[idx] + bvec[idx];
        if (OUTF32) ((float*)outv)[base + idx] = r;
        else        ((short*)outv)[base + idx] = f2bf(r);
    }
}

// ---------------------------------------------------------------------------
// Workspace (84 MB; 102 MB proven safe in R2). Q,K,V contiguous (fused QKV).
// d_out is float* (verified round 4).
// ---------------------------------------------------------------------------
extern "C" void kernel_launch(void* const* d_in, const int* in_sizes, int n_in,
                              void* d_out, int out_size, void* d_ws, size_t ws_size,
                              hipStream_t stream)
{
    const float* X   = (const float*)d_in[0];
    const float* wq  = (const float*)d_in[1];
    const float* wk  = (const float*)d_in[2];
    const float* wv  = (const float*)d_in[3];
    const float* g1  = (const float*)d_in[4];
    const float* b1  = (const float*)d_in[5];
    const float* w1  = (const float*)d_in[6];
    const float* bb1 = (const float*)d_in[7];
    const float* w2  = (const float*)d_in[8];
    const float* bb2 = (const float*)d_in[9];
    const float* g2  = (const float*)d_in[10];
    const float* b2  = (const float*)d_in[11];

    short* ws = (short*)d_ws;
    const size_t E1 = 1048576, E4 = 4194304;
    size_t o = 0;
    short* Xb    = ws + o; o += E4;
    short* wqkvb = ws + o; o += 3*E1;
    short* w1b   = ws + o; o += E4;
    short* w2b   = ws + o; o += E4;
    short* Q     = ws + o; o += E4;
    short* Kb    = ws + o; o += E4;
    short* V     = ws + o; o += E4;
    short* CTX   = ws + o; o += E4;
    short* X1    = ws + o; o += E4;
    short* Y2    = ws + o; o += E4;
    short* Vtr   = ws + o; o += E4;
    short* Hf    = Q;                     // 16M elems, overlays Q..CTX

    dim3 blk(256);
    convert_all<<<dim3(7680), blk, 0, stream>>>(
        X, Xb, wq, wqkvb, wk, wqkvb + E1, wv, wqkvb + 2*E1,
        w1, w1b, w2, w2b);

    gemm128<128,0><<<dim3(MTOK/128, 3072/128), blk, 0, stream>>>(
        Xb, wqkvb, nullptr, nullptr, Q, 3072, DIM);
    transpose_v<<<dim3(SEQ/64, BATCH*NH), blk, 0, stream>>>(V, Vtr);
    attn_kernel<<<dim3(SEQ/128, BATCH*NH), blk, 0, stream>>>(Q, Kb, Vtr, CTX);
    ln_kernel<0><<<dim3(MTOK), blk, 0, stream>>>(X, 1, CTX, g1, b1, X1);
    gemm128<128,1><<<dim3(MTOK/128, DFF/128), blk, 0, stream>>>(
        X1, w1b, bb1, nullptr, Hf, DFF, DIM);
    gemm128<64,2><<<dim3(MTOK/128, DIM/64), blk, 0, stream>>>(
        Hf, w2b, bb2, X1, Y2, DIM, DFF);
    ln_kernel<1><<<dim3(MTOK), blk, 0, stream>>>(Y2, 0, nullptr, g2, b2, d_out);
}

// Round 12
// 331.774 us; speedup vs baseline: 1.0137x; 1.0137x over previous
//
#include <hip/hip_runtime.h>
#include <hip/hip_bf16.h>

#define BATCH 4
#define SEQ   1024
#define DIM   1024
#define NH    16
#define DH    64
#define DFF   4096
#define MTOK  (BATCH*SEQ)   // 4096 token rows

// log2(e)/8 : folded into Q so attention softmax runs in base-2 (exact).
#define QSCALE 0.1803368801111204f

typedef __attribute__((ext_vector_type(8))) short  short8;
typedef __attribute__((ext_vector_type(4))) short  short4v;
typedef __attribute__((ext_vector_type(4))) float  floatx4;
typedef __attribute__((ext_vector_type(4))) float  float4v;
typedef __attribute__((ext_vector_type(4))) int    int4v;

__device__ inline float bf2f(short s) {
    return __uint_as_float(((unsigned int)(unsigned short)s) << 16);
}
__device__ inline short f2bf(float f) {
    __hip_bfloat16 h = __float2bfloat16(f);
    return *reinterpret_cast<short*>(&h);
}

__device__ inline float wave_sum(float v) {
    #pragma unroll
    for (int off = 32; off >= 1; off >>= 1) v += __shfl_xor(v, off);
    return v;
}

// async global->LDS, 16B per lane; LDS dst = wave-uniform base + lane*16.
__device__ inline void async_ld16(short* lds, const short* g) {
    __builtin_amdgcn_global_load_lds(
        (const __attribute__((address_space(1))) void*)g,
        (__attribute__((address_space(3))) void*)lds, 16, 0, 0);
}

// ---------------------------------------------------------------------------
// Fused fp32->bf16 conversion of all 6 tensors in ONE launch.
// ---------------------------------------------------------------------------
__global__ __launch_bounds__(256) void convert_all(
    const float* __restrict__ sX,  short* __restrict__ dX,
    const float* __restrict__ sq,  short* __restrict__ dq,
    const float* __restrict__ sk,  short* __restrict__ dk,
    const float* __restrict__ sv,  short* __restrict__ dv,
    const float* __restrict__ s1,  short* __restrict__ d1,
    const float* __restrict__ s2,  short* __restrict__ d2)
{
    int cid = blockIdx.x * 256 + threadIdx.x;     // 0 .. 1966079
    const float* src; short* dst; int base;
    if      (cid <  524288) { src = sX; dst = dX; base = 0; }
    else if (cid <  655360) { src = sq; dst = dq; base = 524288; }
    else if (cid <  786432) { src = sk; dst = dk; base = 655360; }
    else if (cid <  917504) { src = sv; dst = dv; base = 786432; }
    else if (cid < 1441792) { src = s1; dst = d1; base = 917504; }
    else                    { src = s2; dst = d2; base = 1441792; }
    size_t i = (size_t)(cid - base) * 8;
    float4v f0 = *(const float4v*)(src + i);
    float4v f1 = *(const float4v*)(src + i + 4);
    short8 o;
    o[0]=f2bf(f0[0]); o[1]=f2bf(f0[1]); o[2]=f2bf(f0[2]); o[3]=f2bf(f0[3]);
    o[4]=f2bf(f1[0]); o[5]=f2bf(f1[1]); o[6]=f2bf(f1[2]); o[7]=f2bf(f1[3]);
    *(short8*)(dst + i) = o;
}

// ---------------------------------------------------------------------------
// NT GEMM with REGISTER double-buffering (R10-proven): C[M,N]=A[M,K]*B[N,K]^T,
// bf16, fp32 accum. 128 x BN tile, BK=32, 256 thr (4 waves 2x2).
// Tile k+1 is prefetched global->VGPR before computing tile k from LDS so
// the vmcnt wait lands after the MFMA block (hidden) -- beat both the
// 2-barrier async (R9) and async ping-pong (R11) variants empirically.
// EPI: 0 = QKV split store (Q pre-scaled by QSCALE; V written TRANSPOSED
//          into Vt[bh][d][key], 4-key packed stores -> no transpose kernel)
//      1 = +bias,SELU
//      3 = split-K bf16 partial store (blockIdx.z selects K-half)
// ---------------------------------------------------------------------------
template<int BN, int EPI>
__global__ __launch_bounds__(256) void gemm128(
    const short* __restrict__ A, const short* __restrict__ B,
    const float* __restrict__ bias, const short* __restrict__ resid,
    short* __restrict__ C, int N, int K)
{
    constexpr int NSUB = BN / 32;
    constexpr int LDA  = 40;                       // padded row stride
    __shared__ __align__(16) short As[128*LDA];    // 10 KB
    __shared__ __align__(16) short Bs[BN*LDA];     // 10 / 5 KB

    const int t    = threadIdx.x;
    const int lane = t & 63;
    const int wave = t >> 6;
    const int quad = lane >> 4;
    const int l15  = lane & 15;
    const int wm   = wave & 1;
    const int wn   = wave >> 1;
    const int tm   = blockIdx.x * 128;
    const int tn   = blockIdx.y * BN;

    int kbase = 0, klen = K;
    if (EPI == 3) { klen = K >> 1; kbase = blockIdx.z * klen; }

    const int srow = t >> 2;           // 0..63
    const int skof = (t & 3) * 8;      // k-offset within 32
    const short* Ag0 = A + (size_t)(tm + srow) * K + kbase + skof;
    const short* Ag1 = Ag0 + (size_t)64 * K;
    const short* Bg0 = B + (size_t)(tn + srow) * K + kbase + skof;
    const short* Bg1 = Bg0 + (size_t)64 * K;

    short* Aw0 = &As[srow*LDA + skof];
    short* Aw1 = &As[(64 + srow)*LDA + skof];
    short* Bw0 = &Bs[srow*LDA + skof];
    short* Bw1 = (BN == 128) ? &Bs[(64 + srow)*LDA + skof] : nullptr;

    floatx4 acc[4][NSUB];
    #pragma unroll
    for (int mt = 0; mt < 4; mt++)
        #pragma unroll
        for (int nt = 0; nt < NSUB; nt++) acc[mt][nt] = {0.f, 0.f, 0.f, 0.f};

    // stage tile 0
    int4v pa0 = *(const int4v*)Ag0;
    int4v pa1 = *(const int4v*)Ag1;
    int4v pb0 = *(const int4v*)Bg0;
    int4v pb1;
    if (BN == 128) pb1 = *(const int4v*)Bg1;
    *(int4v*)Aw0 = pa0; *(int4v*)Aw1 = pa1;
    *(int4v*)Bw0 = pb0;
    if (BN == 128) *(int4v*)Bw1 = pb1;
    __syncthreads();

    auto compute = [&]() {
        short8 a[4], b[NSUB];
        #pragma unroll
        for (int mt = 0; mt < 4; mt++)
            a[mt] = *(const short8*)&As[(wm*64 + mt*16 + l15)*LDA + quad*8];
        #pragma unroll
        for (int nt = 0; nt < NSUB; nt++)
            b[nt] = *(const short8*)&Bs[(wn*(BN/2) + nt*16 + l15)*LDA + quad*8];
        #pragma unroll
        for (int mt = 0; mt < 4; mt++)
            #pragma unroll
            for (int nt = 0; nt < NSUB; nt++)
                acc[mt][nt] = __builtin_amdgcn_mfma_f32_16x16x32_bf16(
                                  a[mt], b[nt], acc[mt][nt], 0, 0, 0);
    };

    for (int k0 = 32; k0 < klen; k0 += 32) {
        // prefetch tile k0 into registers (in flight during compute below)
        pa0 = *(const int4v*)(Ag0 + k0);
        pa1 = *(const int4v*)(Ag1 + k0);
        pb0 = *(const int4v*)(Bg0 + k0);
        if (BN == 128) pb1 = *(const int4v*)(Bg1 + k0);
        compute();                         // tile k0-32 from LDS
        __syncthreads();                   // all reads of current tile done
        *(int4v*)Aw0 = pa0; *(int4v*)Aw1 = pa1;
        *(int4v*)Bw0 = pb0;
        if (BN == 128) *(int4v*)Bw1 = pb1;
        __syncthreads();                   // staged tile visible
    }
    compute();                             // last tile

    const float SS = 1.0507009873554805f;
    const float SA = 1.6732632423543772f;

    #pragma unroll
    for (int mt = 0; mt < 4; mt++) {
        #pragma unroll
        for (int nt = 0; nt < NSUB; nt++) {
            int col = tn + wn*(BN/2) + nt*16 + l15;
            if (EPI == 0 && (col >> 10) == 2) {
                // V: packed transposed store -> Vt[bh][d][key]
                int h = (col >> 6) & 15, d = col & 63;
                int row0 = tm + wm*64 + mt*16 + quad*4;
                int b = row0 >> 10, key = row0 & 1023;
                short4v pv;
                #pragma unroll
                for (int r = 0; r < 4; r++) pv[r] = f2bf(acc[mt][nt][r]);
                *(short4v*)&C[(size_t)2*MTOK*1024
                    + ((size_t)(b*16 + h)*64 + d)*1024 + key] = pv;
                continue;
            }
            #pragma unroll
            for (int r = 0; r < 4; r++) {
                int row = tm + wm*64 + mt*16 + quad*4 + r;
                float v = acc[mt][nt][r];
                if (EPI == 0) {
                    int which = col >> 10;
                    if (which == 0) v *= QSCALE;   // base-2 softmax fold
                    C[(size_t)which * ((size_t)MTOK*1024)
                      + (size_t)row * 1024 + (col & 1023)] = f2bf(v);
                } else if (EPI == 1) {
                    v += bias[col];
                    v = (v > 0.f) ? SS * v
                                  : SS * SA * (exp2f(v * 1.44269504f) - 1.f);
                    C[(size_t)row * N + col] = f2bf(v);
                } else {   // EPI == 3: raw bf16 partial
                    C[(size_t)blockIdx.z * ((size_t)MTOK*N)
                      + (size_t)row * N + col] = f2bf(v);
                }
            }
        }
    }
}

// ---------------------------------------------------------------------------
// Split-K reduce for FFN2: Y2 = bf16(P0 + P1 + bias + resid). 8 elems/thr.
// ---------------------------------------------------------------------------
__global__ __launch_bounds__(256) void reduce_ffn2(
    const short* __restrict__ P, const float* __restrict__ bias,
    const short* __restrict__ resid, short* __restrict__ Y)
{
    size_t i = (size_t)(blockIdx.x * 256 + threadIdx.x) * 8;
    short8 p0 = *(const short8*)(P + i);
    short8 p1 = *(const short8*)(P + (size_t)MTOK*1024 + i);
    short8 x1 = *(const short8*)(resid + i);
    int col = (int)(i & 1023);
    float4v b0 = *(const float4v*)(bias + col);
    float4v b1 = *(const float4v*)(bias + col + 4);
    short8 o;
    #pragma unroll
    for (int e = 0; e < 8; e++) {
        float bb = (e < 4) ? b0[e] : b1[e - 4];
        o[e] = f2bf(bf2f(p0[e]) + bf2f(p1[e]) + bb + bf2f(x1[e]));
    }
    *(short8*)(Y + i) = o;
}

// ---------------------------------------------------------------------------
// MFMA flash attention, 128-row Q-tile, ping-pong LDS-staged K/V (R11).
// Base-2 fixed-m softmax, ones-MFMA row-sum. V comes pre-transposed from
// the QKV epilogue (Vt[bh][d][key]). Grid = (SEQ/128, BATCH*NH).
// ---------------------------------------------------------------------------
__global__ __launch_bounds__(256) void attn_kernel(
    const short* __restrict__ Q, const short* __restrict__ K,
    const short* __restrict__ Vt, short* __restrict__ CTX)
{
    __shared__ __align__(16) short Ks[2][64*64];    // [key][d], 2 x 8 KB
    __shared__ __align__(16) short Vs[2][64*64];    // [d][key], 2 x 8 KB
    __shared__ __align__(16) short Pl[4][32][72];   // [wave][qrow][key], 18 KB

    const int t    = threadIdx.x;
    const int lane = t & 63;
    const int wave = t >> 6;
    const int quad = lane >> 4;
    const int l15  = lane & 15;
    const int q0 = (gridDim.x - 1 - blockIdx.x) * 128;   // long blocks first
    const int bh = blockIdx.y;
    const int b  = bh >> 4;
    const int h  = bh & 15;

    const size_t headoff = (size_t)b * SEQ * DIM + (size_t)h * DH;
    const short* Qb  = Q + headoff;
    const short* Kb  = K + headoff;
    const short* Vtb = Vt + (size_t)bh * DH * SEQ;   // [d][key]

    const int wrow0 = q0 + wave*32;                  // wave's first q-row

    short8 aq[2][2];
    #pragma unroll
    for (int mg = 0; mg < 2; mg++)
        #pragma unroll
        for (int c = 0; c < 2; c++)
            aq[mg][c] = *(const short8*)(Qb
                + (size_t)(wrow0 + mg*16 + l15) * DIM + c*32 + quad*8);

    short8 bones;
    {
        short v = (l15 == 0) ? (short)0x3F80 : (short)0;
        #pragma unroll
        for (int e = 0; e < 8; e++) bones[e] = v;
    }

    floatx4 o[2][4], ol[2];
    #pragma unroll
    for (int mg = 0; mg < 2; mg++) {
        #pragma unroll
        for (int nt = 0; nt < 4; nt++) o[mg][nt] = {0.f, 0.f, 0.f, 0.f};
        ol[mg] = {0.f, 0.f, 0.f, 0.f};
    }

    auto stage = [&](int j0, int sb) {
        #pragma unroll
        for (int p = 0; p < 2; p++) {
            async_ld16(Ks[sb] + (t + p*256)*8,
                       Kb + (size_t)(j0 + (t>>3) + p*32) * DIM + (t&7)*8);
            async_ld16(Vs[sb] + (t + p*256)*8,
                       Vtb + (size_t)((t>>3) + p*32) * SEQ + j0 + (t&7)*8);
        }
    };

    const int jend = q0 + 128;
    stage(0, 0);
    __syncthreads();

    int sb = 0;
    for (int j0 = 0; j0 < jend; j0 += 64) {
        if (j0 + 64 < jend) stage(j0 + 64, sb ^ 1);

        if (j0 <= wrow0 + 31) {              // not fully masked for this wave
            floatx4 s[2][4];
            #pragma unroll
            for (int mg = 0; mg < 2; mg++)
                #pragma unroll
                for (int nt = 0; nt < 4; nt++) s[mg][nt] = {0.f, 0.f, 0.f, 0.f};
            #pragma unroll
            for (int c = 0; c < 2; c++) {
                #pragma unroll
                for (int nt = 0; nt < 4; nt++) {
                    short8 bk = *(const short8*)&Ks[sb][(nt*16 + l15)*64 + c*32 + quad*8];
                    s[0][nt] = __builtin_amdgcn_mfma_f32_16x16x32_bf16(aq[0][c], bk, s[0][nt], 0, 0, 0);
                    s[1][nt] = __builtin_amdgcn_mfma_f32_16x16x32_bf16(aq[1][c], bk, s[1][nt], 0, 0, 0);
                }
            }

            if (j0 + 63 > wrow0) {           // diagonal region: causal mask
                #pragma unroll
                for (int mg = 0; mg < 2; mg++) {
                    #pragma unroll
                    for (int nt = 0; nt < 4; nt++) {
                        int col = j0 + nt*16 + l15;
                        #pragma unroll
                        for (int r = 0; r < 4; r++) {
                            int rowq = wrow0 + mg*16 + quad*4 + r;
                            if (col > rowq) s[mg][nt][r] = -1.0e38f;
                        }
                    }
                }
            }

            #pragma unroll
            for (int mg = 0; mg < 2; mg++)
                #pragma unroll
                for (int nt = 0; nt < 4; nt++)
                    #pragma unroll
                    for (int r = 0; r < 4; r++)
                        Pl[wave][mg*16 + quad*4 + r][nt*16 + l15]
                            = f2bf(exp2f(s[mg][nt][r]));

            #pragma unroll
            for (int c = 0; c < 2; c++) {
                short8 ap0 = *(const short8*)&Pl[wave][l15][c*32 + quad*8];
                short8 ap1 = *(const short8*)&Pl[wave][16 + l15][c*32 + quad*8];
                #pragma unroll
                for (int nt = 0; nt < 4; nt++) {
                    short8 bv = *(const short8*)&Vs[sb][(nt*16 + l15)*64 + c*32 + quad*8];
                    o[0][nt] = __builtin_amdgcn_mfma_f32_16x16x32_bf16(ap0, bv, o[0][nt], 0, 0, 0);
                    o[1][nt] = __builtin_amdgcn_mfma_f32_16x16x32_bf16(ap1, bv, o[1][nt], 0, 0, 0);
                }
                ol[0] = __builtin_amdgcn_mfma_f32_16x16x32_bf16(ap0, bones, ol[0], 0, 0, 0);
                ol[1] = __builtin_amdgcn_mfma_f32_16x16x32_bf16(ap1, bones, ol[1], 0, 0, 0);
            }
        }

        __syncthreads();                     // drains vmcnt after compute
        sb ^= 1;
    }

    #pragma unroll
    for (int mg = 0; mg < 2; mg++) {
        float linv[4];
        #pragma unroll
        for (int r = 0; r < 4; r++)
            linv[r] = 1.f / __shfl(ol[mg][r], lane & 48);
        #pragma unroll
        for (int nt = 0; nt < 4; nt++) {
            #pragma unroll
            for (int r = 0; r < 4; r++) {
                int rowq = wrow0 + mg*16 + quad*4 + r;
                int d    = nt*16 + l15;
                CTX[(size_t)b * SEQ * DIM + (size_t)rowq * DIM + h*DH + d]
                    = f2bf(o[mg][nt][r] * linv[r]);
            }
        }
    }
}

// ---------------------------------------------------------------------------
// Row LayerNorm over D=1024. xa fp32 or bf16; optional bf16 residual added.
// OUTF32: 1 -> float out (final), 0 -> bf16 out (intermediate).
// ---------------------------------------------------------------------------
template<int OUTF32>
__global__ __launch_bounds__(256) void ln_kernel(
    const void* __restrict__ xav, int xa_fp32, const short* __restrict__ xb,
    const float* __restrict__ g, const float* __restrict__ bvec,
    void* __restrict__ outv)
{
    __shared__ float red[8];
    const size_t base = (size_t)blockIdx.x * DIM;
    const int wave = threadIdx.x >> 6;

    float x[4];
    float sum = 0.f, sq = 0.f;
    #pragma unroll
    for (int i = 0; i < 4; i++) {
        int idx = threadIdx.x + i*256;
        float v = xa_fp32 ? ((const float*)xav)[base + idx]
                          : bf2f(((const short*)xav)[base + idx]);
        if (xb) v += bf2f(xb[base + idx]);
        x[i] = v; sum += v; sq += v*v;
    }
    sum = wave_sum(sum); sq = wave_sum(sq);
    if ((threadIdx.x & 63) == 0) { red[wave] = sum; red[4 + wave] = sq; }
    __syncthreads();
    float s1 = red[0] + red[1] + red[2] + red[3];
    float s2 = red[4] + red[5] + red[6] + red[7];
    float mean = s1 * (1.f / DIM);
    float var  = s2 * (1.f / DIM) - mean * mean;
    float rstd = rsqrtf(var + 1e-5f);
    #pragma unroll
    for (int i = 0; i < 4; i++) {
        int idx = threadIdx.x + i*256;
        float r = (x[i] - mean) * rstd * g[idx] + bvec[idx];
        if (OUTF32) ((float*)outv)[base + idx] = r;
        else        ((short*)outv)[base + idx] = f2bf(r);
    }
}

// ---------------------------------------------------------------------------
// Workspace (94 MB; 102 MB proven safe in R2). Q | K | Vt contiguous
// (fused QKV epilogue writes V pre-transposed). P = split-K partials.
// d_out is float* (verified round 4).
// ---------------------------------------------------------------------------
extern "C" void kernel_launch(void* const* d_in, const int* in_sizes, int n_in,
                              void* d_out, int out_size, void* d_ws, size_t ws_size,
                              hipStream_t stream)
{
    const float* X   = (const float*)d_in[0];
    const float* wq  = (const float*)d_in[1];
    const float* wk  = (const float*)d_in[2];
    const float* wv  = (const float*)d_in[3];
    const float* g1  = (const float*)d_in[4];
    const float* b1  = (const float*)d_in[5];
    const float* w1  = (const float*)d_in[6];
    const float* bb1 = (const float*)d_in[7];
    const float* w2  = (const float*)d_in[8];
    const float* bb2 = (const float*)d_in[9];
    const float* g2  = (const float*)d_in[10];
    const float* b2  = (const float*)d_in[11];

    short* ws = (short*)d_ws;
    const size_t E1 = 1048576, E4 = 4194304;
    size_t o = 0;
    short* Xb    = ws + o; o += E4;
    short* wqkvb = ws + o; o += 3*E1;
    short* w1b   = ws + o; o += E4;
    short* w2b   = ws + o; o += E4;
    short* Q     = ws + o; o += E4;   // Q | K | Vt contiguous
    short* Kb    = ws + o; o += E4;
    short* Vt    = ws + o; o += E4;
    short* CTX   = ws + o; o += E4;
    short* X1    = ws + o; o += E4;
    short* Y2    = ws + o; o += E4;
    short* P     = ws + o; o += 2*E4; // split-K partials (bf16)
    short* Hf    = Q;                 // 16M elems, overlays Q..CTX

    dim3 blk(256);
    convert_all<<<dim3(7680), blk, 0, stream>>>(
        X, Xb, wq, wqkvb, wk, wqkvb + E1, wv, wqkvb + 2*E1,
        w1, w1b, w2, w2b);

    gemm128<128,0><<<dim3(MTOK/128, 3072/128), blk, 0, stream>>>(
        Xb, wqkvb, nullptr, nullptr, Q, 3072, DIM);
    attn_kernel<<<dim3(SEQ/128, BATCH*NH), blk, 0, stream>>>(Q, Kb, Vt, CTX);
    ln_kernel<0><<<dim3(MTOK), blk, 0, stream>>>(X, 1, CTX, g1, b1, X1);
    gemm128<128,1><<<dim3(MTOK/128, DFF/128), blk, 0, stream>>>(
        X1, w1b, bb1, nullptr, Hf, DFF, DIM);
    gemm128<64,3><<<dim3(MTOK/128, DIM/64, 2), blk, 0, stream>>>(
        Hf, w2b, nullptr, nullptr, P, DIM, DFF);
    reduce_ffn2<<<dim3(E4/2048), blk, 0, stream>>>(P, bb2, X1, Y2);
    ln_kernel<1><<<dim3(MTOK), blk, 0, stream>>>(Y2, 0, nullptr, g2, b2, d_out);
}

// Round 13
// 324.865 us; speedup vs baseline: 1.0352x; 1.0213x over previous
//
#include <hip/hip_runtime.h>
#include <hip/hip_bf16.h>

#define BATCH 4
#define SEQ   1024
#define DIM   1024
#define NH    16
#define DH    64
#define DFF   4096
#define MTOK  (BATCH*SEQ)   // 4096 token rows

// log2(e)/8 : folded into Q so attention softmax runs in base-2 (exact).
#define QSCALE 0.1803368801111204f

typedef __attribute__((ext_vector_type(8))) short  short8;
typedef __attribute__((ext_vector_type(4))) short  short4v;
typedef __attribute__((ext_vector_type(4))) float  floatx4;
typedef __attribute__((ext_vector_type(4))) float  float4v;
typedef __attribute__((ext_vector_type(4))) int    int4v;

__device__ inline float bf2f(short s) {
    return __uint_as_float(((unsigned int)(unsigned short)s) << 16);
}
__device__ inline short f2bf(float f) {
    __hip_bfloat16 h = __float2bfloat16(f);
    return *reinterpret_cast<short*>(&h);
}

__device__ inline float wave_sum(float v) {
    #pragma unroll
    for (int off = 32; off >= 1; off >>= 1) v += __shfl_xor(v, off);
    return v;
}

// async global->LDS, 16B per lane; LDS dst = wave-uniform base + lane*16.
__device__ inline void async_ld16(short* lds, const short* g) {
    __builtin_amdgcn_global_load_lds(
        (const __attribute__((address_space(1))) void*)g,
        (__attribute__((address_space(3))) void*)lds, 16, 0, 0);
}

// ---------------------------------------------------------------------------
// Fused fp32->bf16 conversion of all 6 tensors in ONE launch.
// ---------------------------------------------------------------------------
__global__ __launch_bounds__(256) void convert_all(
    const float* __restrict__ sX,  short* __restrict__ dX,
    const float* __restrict__ sq,  short* __restrict__ dq,
    const float* __restrict__ sk,  short* __restrict__ dk,
    const float* __restrict__ sv,  short* __restrict__ dv,
    const float* __restrict__ s1,  short* __restrict__ d1,
    const float* __restrict__ s2,  short* __restrict__ d2)
{
    int cid = blockIdx.x * 256 + threadIdx.x;     // 0 .. 1966079
    const float* src; short* dst; int base;
    if      (cid <  524288) { src = sX; dst = dX; base = 0; }
    else if (cid <  655360) { src = sq; dst = dq; base = 524288; }
    else if (cid <  786432) { src = sk; dst = dk; base = 655360; }
    else if (cid <  917504) { src = sv; dst = dv; base = 786432; }
    else if (cid < 1441792) { src = s1; dst = d1; base = 917504; }
    else                    { src = s2; dst = d2; base = 1441792; }
    size_t i = (size_t)(cid - base) * 8;
    float4v f0 = *(const float4v*)(src + i);
    float4v f1 = *(const float4v*)(src + i + 4);
    short8 o;
    o[0]=f2bf(f0[0]); o[1]=f2bf(f0[1]); o[2]=f2bf(f0[2]); o[3]=f2bf(f0[3]);
    o[4]=f2bf(f1[0]); o[5]=f2bf(f1[1]); o[6]=f2bf(f1[2]); o[7]=f2bf(f1[3]);
    *(short8*)(dst + i) = o;
}

// ---------------------------------------------------------------------------
// NT GEMM with REGISTER double-buffering (R10-proven): C[M,N]=A[M,K]*B[N,K]^T,
// bf16, fp32 accum. 128 x BN tile, BK=32, 256 thr (4 waves 2x2).
// EPI: 0 = QKV split store (Q pre-scaled by QSCALE; V written TRANSPOSED
//          into Vt[bh][d][key]); 1 = +bias,SELU;
//      3 = split-K bf16 partial store (blockIdx.z selects K quarter)
// ---------------------------------------------------------------------------
template<int BN, int EPI>
__global__ __launch_bounds__(256) void gemm128(
    const short* __restrict__ A, const short* __restrict__ B,
    const float* __restrict__ bias, const short* __restrict__ resid,
    short* __restrict__ C, int N, int K)
{
    constexpr int NSUB = BN / 32;
    constexpr int LDA  = 40;                       // padded row stride
    __shared__ __align__(16) short As[128*LDA];    // 10 KB
    __shared__ __align__(16) short Bs[BN*LDA];     // 10 / 5 KB

    const int t    = threadIdx.x;
    const int lane = t & 63;
    const int wave = t >> 6;
    const int quad = lane >> 4;
    const int l15  = lane & 15;
    const int wm   = wave & 1;
    const int wn   = wave >> 1;
    const int tm   = blockIdx.x * 128;
    const int tn   = blockIdx.y * BN;

    int kbase = 0, klen = K;
    if (EPI == 3) { klen = K >> 2; kbase = blockIdx.z * klen; }

    const int srow = t >> 2;           // 0..63
    const int skof = (t & 3) * 8;      // k-offset within 32
    const short* Ag0 = A + (size_t)(tm + srow) * K + kbase + skof;
    const short* Ag1 = Ag0 + (size_t)64 * K;
    const short* Bg0 = B + (size_t)(tn + srow) * K + kbase + skof;
    const short* Bg1 = Bg0 + (size_t)64 * K;

    short* Aw0 = &As[srow*LDA + skof];
    short* Aw1 = &As[(64 + srow)*LDA + skof];
    short* Bw0 = &Bs[srow*LDA + skof];
    short* Bw1 = (BN == 128) ? &Bs[(64 + srow)*LDA + skof] : nullptr;

    floatx4 acc[4][NSUB];
    #pragma unroll
    for (int mt = 0; mt < 4; mt++)
        #pragma unroll
        for (int nt = 0; nt < NSUB; nt++) acc[mt][nt] = {0.f, 0.f, 0.f, 0.f};

    // stage tile 0
    int4v pa0 = *(const int4v*)Ag0;
    int4v pa1 = *(const int4v*)Ag1;
    int4v pb0 = *(const int4v*)Bg0;
    int4v pb1;
    if (BN == 128) pb1 = *(const int4v*)Bg1;
    *(int4v*)Aw0 = pa0; *(int4v*)Aw1 = pa1;
    *(int4v*)Bw0 = pb0;
    if (BN == 128) *(int4v*)Bw1 = pb1;
    __syncthreads();

    auto compute = [&]() {
        short8 a[4], b[NSUB];
        #pragma unroll
        for (int mt = 0; mt < 4; mt++)
            a[mt] = *(const short8*)&As[(wm*64 + mt*16 + l15)*LDA + quad*8];
        #pragma unroll
        for (int nt = 0; nt < NSUB; nt++)
            b[nt] = *(const short8*)&Bs[(wn*(BN/2) + nt*16 + l15)*LDA + quad*8];
        #pragma unroll
        for (int mt = 0; mt < 4; mt++)
            #pragma unroll
            for (int nt = 0; nt < NSUB; nt++)
                acc[mt][nt] = __builtin_amdgcn_mfma_f32_16x16x32_bf16(
                                  a[mt], b[nt], acc[mt][nt], 0, 0, 0);
    };

    for (int k0 = 32; k0 < klen; k0 += 32) {
        // prefetch tile k0 into registers (in flight during compute below)
        pa0 = *(const int4v*)(Ag0 + k0);
        pa1 = *(const int4v*)(Ag1 + k0);
        pb0 = *(const int4v*)(Bg0 + k0);
        if (BN == 128) pb1 = *(const int4v*)(Bg1 + k0);
        compute();                         // tile k0-32 from LDS
        __syncthreads();                   // all reads of current tile done
        *(int4v*)Aw0 = pa0; *(int4v*)Aw1 = pa1;
        *(int4v*)Bw0 = pb0;
        if (BN == 128) *(int4v*)Bw1 = pb1;
        __syncthreads();                   // staged tile visible
    }
    compute();                             // last tile

    const float SS = 1.0507009873554805f;
    const float SA = 1.6732632423543772f;

    #pragma unroll
    for (int mt = 0; mt < 4; mt++) {
        #pragma unroll
        for (int nt = 0; nt < NSUB; nt++) {
            int col = tn + wn*(BN/2) + nt*16 + l15;
            if (EPI == 0 && (col >> 10) == 2) {
                // V: packed transposed store -> Vt[bh][d][key]
                int h = (col >> 6) & 15, d = col & 63;
                int row0 = tm + wm*64 + mt*16 + quad*4;
                int b = row0 >> 10, key = row0 & 1023;
                short4v pv;
                #pragma unroll
                for (int r = 0; r < 4; r++) pv[r] = f2bf(acc[mt][nt][r]);
                *(short4v*)&C[(size_t)2*MTOK*1024
                    + ((size_t)(b*16 + h)*64 + d)*1024 + key] = pv;
                continue;
            }
            #pragma unroll
            for (int r = 0; r < 4; r++) {
                int row = tm + wm*64 + mt*16 + quad*4 + r;
                float v = acc[mt][nt][r];
                if (EPI == 0) {
                    int which = col >> 10;
                    if (which == 0) v *= QSCALE;   // base-2 softmax fold
                    C[(size_t)which * ((size_t)MTOK*1024)
                      + (size_t)row * 1024 + (col & 1023)] = f2bf(v);
                } else if (EPI == 1) {
                    v += bias[col];
                    v = (v > 0.f) ? SS * v
                                  : SS * SA * (exp2f(v * 1.44269504f) - 1.f);
                    C[(size_t)row * N + col] = f2bf(v);
                } else {   // EPI == 3: raw bf16 partial, quarter z
                    C[(size_t)blockIdx.z * ((size_t)MTOK*N)
                      + (size_t)row * N + col] = f2bf(v);
                }
            }
        }
    }
}

// ---------------------------------------------------------------------------
// MFMA flash attention, 128-row Q-tile, ping-pong LDS-staged K/V.
// Base-2 fixed-m softmax, ones-MFMA row-sum. V pre-transposed by QKV
// epilogue (Vt[bh][d][key]). Grid = (SEQ/128, BATCH*NH).
// ---------------------------------------------------------------------------
__global__ __launch_bounds__(256) void attn_kernel(
    const short* __restrict__ Q, const short* __restrict__ K,
    const short* __restrict__ Vt, short* __restrict__ CTX)
{
    __shared__ __align__(16) short Ks[2][64*64];    // [key][d], 2 x 8 KB
    __shared__ __align__(16) short Vs[2][64*64];    // [d][key], 2 x 8 KB
    __shared__ __align__(16) short Pl[4][32][72];   // [wave][qrow][key], 18 KB

    const int t    = threadIdx.x;
    const int lane = t & 63;
    const int wave = t >> 6;
    const int quad = lane >> 4;
    const int l15  = lane & 15;
    const int q0 = (gridDim.x - 1 - blockIdx.x) * 128;   // long blocks first
    const int bh = blockIdx.y;
    const int b  = bh >> 4;
    const int h  = bh & 15;

    const size_t headoff = (size_t)b * SEQ * DIM + (size_t)h * DH;
    const short* Qb  = Q + headoff;
    const short* Kb  = K + headoff;
    const short* Vtb = Vt + (size_t)bh * DH * SEQ;   // [d][key]

    const int wrow0 = q0 + wave*32;                  // wave's first q-row

    short8 aq[2][2];
    #pragma unroll
    for (int mg = 0; mg < 2; mg++)
        #pragma unroll
        for (int c = 0; c < 2; c++)
            aq[mg][c] = *(const short8*)(Qb
                + (size_t)(wrow0 + mg*16 + l15) * DIM + c*32 + quad*8);

    short8 bones;
    {
        short v = (l15 == 0) ? (short)0x3F80 : (short)0;
        #pragma unroll
        for (int e = 0; e < 8; e++) bones[e] = v;
    }

    floatx4 o[2][4], ol[2];
    #pragma unroll
    for (int mg = 0; mg < 2; mg++) {
        #pragma unroll
        for (int nt = 0; nt < 4; nt++) o[mg][nt] = {0.f, 0.f, 0.f, 0.f};
        ol[mg] = {0.f, 0.f, 0.f, 0.f};
    }

    auto stage = [&](int j0, int sb) {
        #pragma unroll
        for (int p = 0; p < 2; p++) {
            async_ld16(Ks[sb] + (t + p*256)*8,
                       Kb + (size_t)(j0 + (t>>3) + p*32) * DIM + (t&7)*8);
            async_ld16(Vs[sb] + (t + p*256)*8,
                       Vtb + (size_t)((t>>3) + p*32) * SEQ + j0 + (t&7)*8);
        }
    };

    const int jend = q0 + 128;
    stage(0, 0);
    __syncthreads();

    int sb = 0;
    for (int j0 = 0; j0 < jend; j0 += 64) {
        if (j0 + 64 < jend) stage(j0 + 64, sb ^ 1);

        if (j0 <= wrow0 + 31) {              // not fully masked for this wave
            floatx4 s[2][4];
            #pragma unroll
            for (int mg = 0; mg < 2; mg++)
                #pragma unroll
                for (int nt = 0; nt < 4; nt++) s[mg][nt] = {0.f, 0.f, 0.f, 0.f};
            #pragma unroll
            for (int c = 0; c < 2; c++) {
                #pragma unroll
                for (int nt = 0; nt < 4; nt++) {
                    short8 bk = *(const short8*)&Ks[sb][(nt*16 + l15)*64 + c*32 + quad*8];
                    s[0][nt] = __builtin_amdgcn_mfma_f32_16x16x32_bf16(aq[0][c], bk, s[0][nt], 0, 0, 0);
                    s[1][nt] = __builtin_amdgcn_mfma_f32_16x16x32_bf16(aq[1][c], bk, s[1][nt], 0, 0, 0);
                }
            }

            if (j0 + 63 > wrow0) {           // diagonal region: causal mask
                #pragma unroll
                for (int mg = 0; mg < 2; mg++) {
                    #pragma unroll
                    for (int nt = 0; nt < 4; nt++) {
                        int col = j0 + nt*16 + l15;
                        #pragma unroll
                        for (int r = 0; r < 4; r++) {
                            int rowq = wrow0 + mg*16 + quad*4 + r;
                            if (col > rowq) s[mg][nt][r] = -1.0e38f;
                        }
                    }
                }
            }

            #pragma unroll
            for (int mg = 0; mg < 2; mg++)
                #pragma unroll
                for (int nt = 0; nt < 4; nt++)
                    #pragma unroll
                    for (int r = 0; r < 4; r++)
                        Pl[wave][mg*16 + quad*4 + r][nt*16 + l15]
                            = f2bf(exp2f(s[mg][nt][r]));

            #pragma unroll
            for (int c = 0; c < 2; c++) {
                short8 ap0 = *(const short8*)&Pl[wave][l15][c*32 + quad*8];
                short8 ap1 = *(const short8*)&Pl[wave][16 + l15][c*32 + quad*8];
                #pragma unroll
                for (int nt = 0; nt < 4; nt++) {
                    short8 bv = *(const short8*)&Vs[sb][(nt*16 + l15)*64 + c*32 + quad*8];
                    o[0][nt] = __builtin_amdgcn_mfma_f32_16x16x32_bf16(ap0, bv, o[0][nt], 0, 0, 0);
                    o[1][nt] = __builtin_amdgcn_mfma_f32_16x16x32_bf16(ap1, bv, o[1][nt], 0, 0, 0);
                }
                ol[0] = __builtin_amdgcn_mfma_f32_16x16x32_bf16(ap0, bones, ol[0], 0, 0, 0);
                ol[1] = __builtin_amdgcn_mfma_f32_16x16x32_bf16(ap1, bones, ol[1], 0, 0, 0);
            }
        }

        __syncthreads();                     // drains vmcnt after compute
        sb ^= 1;
    }

    #pragma unroll
    for (int mg = 0; mg < 2; mg++) {
        float linv[4];
        #pragma unroll
        for (int r = 0; r < 4; r++)
            linv[r] = 1.f / __shfl(ol[mg][r], lane & 48);
        #pragma unroll
        for (int nt = 0; nt < 4; nt++) {
            #pragma unroll
            for (int r = 0; r < 4; r++) {
                int rowq = wrow0 + mg*16 + quad*4 + r;
                int d    = nt*16 + l15;
                CTX[(size_t)b * SEQ * DIM + (size_t)rowq * DIM + h*DH + d]
                    = f2bf(o[mg][nt][r] * linv[r]);
            }
        }
    }
}

// ---------------------------------------------------------------------------
// LN1: row LayerNorm over D=1024 of (X fp32 + CTX bf16), bf16 out.
// ---------------------------------------------------------------------------
__global__ __launch_bounds__(256) void ln1_kernel(
    const float* __restrict__ X, const short* __restrict__ ctx,
    const float* __restrict__ g, const float* __restrict__ bvec,
    short* __restrict__ out)
{
    __shared__ float red[8];
    const size_t base = (size_t)blockIdx.x * DIM;
    const int wave = threadIdx.x >> 6;

    float x[4];
    float sum = 0.f, sq = 0.f;
    #pragma unroll
    for (int i = 0; i < 4; i++) {
        int idx = threadIdx.x + i*256;
        float v = X[base + idx] + bf2f(ctx[base + idx]);
        x[i] = v; sum += v; sq += v*v;
    }
    sum = wave_sum(sum); sq = wave_sum(sq);
    if ((threadIdx.x & 63) == 0) { red[wave] = sum; red[4 + wave] = sq; }
    __syncthreads();
    float s1 = red[0] + red[1] + red[2] + red[3];
    float s2 = red[4] + red[5] + red[6] + red[7];
    float mean = s1 * (1.f / DIM);
    float var  = s2 * (1.f / DIM) - mean * mean;
    float rstd = rsqrtf(var + 1e-5f);
    #pragma unroll
    for (int i = 0; i < 4; i++) {
        int idx = threadIdx.x + i*256;
        out[base + idx] = f2bf((x[i] - mean) * rstd * g[idx] + bvec[idx]);
    }
}

// ---------------------------------------------------------------------------
// LN2 fused with split-K reduce: x = P0+P1+P2+P3 (bf16 partials) + bias +
// X1 (residual), then LayerNorm, fp32 out to d_out.
// ---------------------------------------------------------------------------
__global__ __launch_bounds__(256) void ln2_fused(
    const short* __restrict__ P, const float* __restrict__ bias,
    const short* __restrict__ x1, const float* __restrict__ g,
    const float* __restrict__ bvec, float* __restrict__ out)
{
    __shared__ float red[8];
    const size_t base = (size_t)blockIdx.x * DIM;
    const size_t E4 = (size_t)MTOK * 1024;
    const int wave = threadIdx.x >> 6;

    float x[4];
    float sum = 0.f, sq = 0.f;
    #pragma unroll
    for (int i = 0; i < 4; i++) {
        int idx = threadIdx.x + i*256;
        size_t p = base + idx;
        float v = bf2f(P[p]) + bf2f(P[E4 + p]) + bf2f(P[2*E4 + p])
                + bf2f(P[3*E4 + p]) + bias[idx] + bf2f(x1[p]);
        x[i] = v; sum += v; sq += v*v;
    }
    sum = wave_sum(sum); sq = wave_sum(sq);
    if ((threadIdx.x & 63) == 0) { red[wave] = sum; red[4 + wave] = sq; }
    __syncthreads();
    float s1 = red[0] + red[1] + red[2] + red[3];
    float s2 = red[4] + red[5] + red[6] + red[7];
    float mean = s1 * (1.f / DIM);
    float var  = s2 * (1.f / DIM) - mean * mean;
    float rstd = rsqrtf(var + 1e-5f);
    #pragma unroll
    for (int i = 0; i < 4; i++) {
        int idx = threadIdx.x + i*256;
        out[base + idx] = (x[i] - mean) * rstd * g[idx] + bvec[idx];
    }
}

// ---------------------------------------------------------------------------
// Workspace (102 MB -- exactly R2's proven-safe footprint).
// Q | K | Vt contiguous (fused QKV epilogue). P = 4 split-K partials.
// d_out is float* (verified round 4).
// ---------------------------------------------------------------------------
extern "C" void kernel_launch(void* const* d_in, const int* in_sizes, int n_in,
                              void* d_out, int out_size, void* d_ws, size_t ws_size,
                              hipStream_t stream)
{
    const float* X   = (const float*)d_in[0];
    const float* wq  = (const float*)d_in[1];
    const float* wk  = (const float*)d_in[2];
    const float* wv  = (const float*)d_in[3];
    const float* g1  = (const float*)d_in[4];
    const float* b1  = (const float*)d_in[5];
    const float* w1  = (const float*)d_in[6];
    const float* bb1 = (const float*)d_in[7];
    const float* w2  = (const float*)d_in[8];
    const float* bb2 = (const float*)d_in[9];
    const float* g2  = (const float*)d_in[10];
    const float* b2  = (const float*)d_in[11];

    short* ws = (short*)d_ws;
    const size_t E1 = 1048576, E4 = 4194304;
    size_t o = 0;
    short* Xb    = ws + o; o += E4;
    short* wqkvb = ws + o; o += 3*E1;
    short* w1b   = ws + o; o += E4;
    short* w2b   = ws + o; o += E4;
    short* Q     = ws + o; o += E4;   // Q | K | Vt contiguous
    short* Kb    = ws + o; o += E4;
    short* Vt    = ws + o; o += E4;
    short* CTX   = ws + o; o += E4;
    short* X1    = ws + o; o += E4;
    short* P     = ws + o; o += 4*E4; // split-K=4 partials (bf16)
    short* Hf    = Q;                 // 16M elems, overlays Q..CTX

    dim3 blk(256);
    convert_all<<<dim3(7680), blk, 0, stream>>>(
        X, Xb, wq, wqkvb, wk, wqkvb + E1, wv, wqkvb + 2*E1,
        w1, w1b, w2, w2b);

    gemm128<128,0><<<dim3(MTOK/128, 3072/128), blk, 0, stream>>>(
        Xb, wqkvb, nullptr, nullptr, Q, 3072, DIM);
    attn_kernel<<<dim3(SEQ/128, BATCH*NH), blk, 0, stream>>>(Q, Kb, Vt, CTX);
    ln1_kernel<<<dim3(MTOK), blk, 0, stream>>>(X, CTX, g1, b1, X1);
    gemm128<128,1><<<dim3(MTOK/128, DFF/128), blk, 0, stream>>>(
        X1, w1b, bb1, nullptr, Hf, DFF, DIM);
    gemm128<128,3><<<dim3(MTOK/128, DIM/128, 4), blk, 0, stream>>>(
        Hf, w2b, nullptr, nullptr, P, DIM, DFF);
    ln2_fused<<<dim3(MTOK), blk, 0, stream>>>(P, bb2, X1, g2, b2, (float*)d_out);
}